// Round 5
// baseline (357.890 us; speedup 1.0000x reference)
//
#include <hip/hip_runtime.h>

// B=16384 bags, HIST=50, K=128, EMB_DIM=3.
// v5: access-ORDER-optimized gather, simplified pipeline (no scan kernel).
// Hypothesis under test: the random 819K-row gather from the 120 MB table
// (swept out of L3 every iter by the 480 MB harness poison fill) is
// DRAM-row-activate bound (~0.9 TB/s effective). Bucket indices by idx>>10
// (16384 buckets x 12 KB table span, FIXED capacity 128 + spill list), then
// gather in bucket order => ascending table addresses => row-buffer hits.
// Per-bag sums via atomicAdd into tmp[B][3] (order-independent, L2-hot).
//
// 4 dispatches, all 256-thread blocks, stream-ordered, graph-capture safe:
//   K1 zero -> K2 bucket-scatter -> K3 ordered gather -> K4 finalize
// Fallback: verified v3 single-kernel path if ws is too small.

#define KDIM 128
#define NB   16384          // buckets; idx < 10M -> idx>>10 < 9766 <= NB
#define CAP  128            // slots per bucket (expected 50; spill backs rest)

struct F3 { float x, y, z; };   // 12-byte row; global_load_dwordx3

// --- K1: zero counts + spill cursor + tmp -----------------------------------
__global__ __launch_bounds__(256) void zero_kernel(
    unsigned int* __restrict__ counts, unsigned int* __restrict__ spill_cnt,
    float* __restrict__ tmp, int ntmp) {
    const int i = blockIdx.x * blockDim.x + threadIdx.x;
    if (i < NB) counts[i] = 0u;
    if (i < ntmp) tmp[i] = 0.f;
    if (i == 0) spill_cnt[0] = 0u;
}

// --- K2: scatter (idx,bag) into fixed-capacity buckets ----------------------
__global__ __launch_bounds__(256) void scatter_kernel(
    const int* __restrict__ eb_input, const int* __restrict__ eb_offset,
    unsigned int* __restrict__ counts, unsigned int* __restrict__ spill_cnt,
    unsigned long long* __restrict__ pairs, unsigned long long* __restrict__ spill,
    int n, int num_bags) {
    const int p = blockIdx.x * blockDim.x + threadIdx.x;
    if (p >= n) return;
    const unsigned int idx = (unsigned)eb_input[p];
    // largest bag with eb_offset[bag] <= p (offsets sorted, offset[0]=0)
    int lo = 0, hi = num_bags - 1;
    while (lo < hi) {
        const int mid = (lo + hi + 1) >> 1;
        if (eb_offset[mid] <= p) lo = mid; else hi = mid - 1;
    }
    const unsigned long long pk = ((unsigned long long)idx << 32) | (unsigned)lo;
    const unsigned int b = idx >> 10;
    const unsigned int c = atomicAdd(&counts[b], 1u);
    if (c < CAP) {
        pairs[(size_t)b * CAP + c] = pk;
    } else {
        const unsigned int sc = atomicAdd(spill_cnt, 1u);  // sc < n always
        spill[sc] = pk;
    }
}

// --- K3: gather in ascending-bucket (=ascending address) order --------------
__global__ __launch_bounds__(256) void gather_kernel(
    const unsigned long long* __restrict__ pairs,
    const unsigned long long* __restrict__ spill,
    const unsigned int* __restrict__ counts,
    const unsigned int* __restrict__ spill_cnt,
    const float* __restrict__ emb_weight,
    float* __restrict__ tmp, int n) {
    const long long i = (long long)blockIdx.x * blockDim.x + threadIdx.x;
    unsigned long long pk;
    if (i < (long long)NB * CAP) {
        const unsigned int b = (unsigned int)(i >> 7);      // CAP = 128
        const unsigned int j = (unsigned int)(i & (CAP - 1));
        const unsigned int cb = counts[b];
        if (j >= (cb < CAP ? cb : CAP)) return;
        pk = pairs[i];
    } else {
        const long long k = i - (long long)NB * CAP;
        if (k >= (long long)spill_cnt[0]) return;
        pk = spill[k];
    }
    const unsigned int idx = (unsigned int)(pk >> 32);
    const unsigned int bag = (unsigned int)(pk & 0xffffffffu);
    const F3 r = *(const F3*)(emb_weight + (size_t)idx * 3);
    atomicAdd(&tmp[bag * 3 + 0], r.x);
    atomicAdd(&tmp[bag * 3 + 1], r.y);
    atomicAdd(&tmp[bag * 3 + 2], r.z);
}

// --- K4: finalize — mean + collapsed MLP (verified v3 epilogue) -------------
__global__ __launch_bounds__(256) void finalize_kernel(
    const int* __restrict__ eb_offset,
    const float* __restrict__ mlp_input,  // [B, 128]
    const float* __restrict__ tmp,        // [B, 3] sums
    const float* __restrict__ w0, const float* __restrict__ b0,
    const float* __restrict__ w1, const float* __restrict__ b1,
    const float* __restrict__ w2, const float* __restrict__ b2,
    float* __restrict__ out,              // [B, 12]
    int n_indices, int num_bags)
{
    __shared__ float wsT[KDIM * 4];
    __shared__ float bc[4];

    const int tid = threadIdx.x;
    if (tid < KDIM) {
        float t[6];
        #pragma unroll
        for (int i = 0; i < 6; ++i) {
            float acc = 0.f;
            #pragma unroll
            for (int j = 0; j < 12; ++j)
                acc += w1[i * 12 + j] * w0[j * KDIM + tid];
            t[i] = acc;
        }
        #pragma unroll
        for (int o = 0; o < 3; ++o) {
            float acc = 0.f;
            #pragma unroll
            for (int i = 0; i < 6; ++i)
                acc += w2[o * 6 + i] * t[i];
            wsT[tid * 4 + o] = acc;
        }
        wsT[tid * 4 + 3] = 0.f;
        if (tid == 0) {
            float tb[6];
            #pragma unroll
            for (int i = 0; i < 6; ++i) {
                float acc = 0.f;
                #pragma unroll
                for (int j = 0; j < 12; ++j)
                    acc += w1[i * 12 + j] * b0[j];
                tb[i] = acc + b1[i];
            }
            #pragma unroll
            for (int o = 0; o < 3; ++o) {
                float acc = 0.f;
                #pragma unroll
                for (int i = 0; i < 6; ++i)
                    acc += w2[o * 6 + i] * tb[i];
                bc[o] = acc + b2[o];
            }
            bc[3] = 0.f;
        }
    }
    __syncthreads();

    const int lane = tid & 63;
    const int wave = tid >> 6;
    const int bag  = blockIdx.x * (blockDim.x >> 6) + wave;
    if (bag >= num_bags) return;

    const int start = eb_offset[bag];
    const int end   = (bag + 1 < num_bags) ? eb_offset[bag + 1] : n_indices;
    const int cnt   = end - start;

    const float2 x  = *(const float2*)(mlp_input + bag * KDIM + lane * 2);
    const float4 t0 = *(const float4*)(wsT + lane * 8);
    const float4 t1 = *(const float4*)(wsT + lane * 8 + 4);
    float m0 = x.x * t0.x + x.y * t1.x;
    float m1 = x.x * t0.y + x.y * t1.y;
    float m2 = x.x * t0.z + x.y * t1.z;

    #pragma unroll
    for (int off = 1; off <= 32; off <<= 1) {
        m0 += __shfl_xor(m0, off, 64);
        m1 += __shfl_xor(m1, off, 64);
        m2 += __shfl_xor(m2, off, 64);
    }

    if (lane < 12) {
        float v;
        if (lane < 9) {
            const float inv = 1.0f / fmaxf((float)cnt, 1.0f);
            v = tmp[bag * 3 + (lane % 3)] * inv;
        } else {
            const int cc = lane - 9;
            v = (cc == 0 ? m0 : (cc == 1 ? m1 : m2)) + bc[cc];
        }
        out[bag * 12 + lane] = v;
    }
}

// --- Fallback: verified v3 single-kernel path -------------------------------
__global__ __launch_bounds__(256) void fused_embbag_mlp_kernel(
    const int* __restrict__ eb_input, const int* __restrict__ eb_offset,
    const float* __restrict__ mlp_input, const float* __restrict__ emb_weight,
    const float* __restrict__ w0, const float* __restrict__ b0,
    const float* __restrict__ w1, const float* __restrict__ b1,
    const float* __restrict__ w2, const float* __restrict__ b2,
    float* __restrict__ out, int n_indices, int num_bags)
{
    __shared__ float wsT[KDIM * 4];
    __shared__ float bc[4];
    const int tid = threadIdx.x;
    if (tid < KDIM) {
        float t[6];
        #pragma unroll
        for (int i = 0; i < 6; ++i) {
            float acc = 0.f;
            #pragma unroll
            for (int j = 0; j < 12; ++j)
                acc += w1[i * 12 + j] * w0[j * KDIM + tid];
            t[i] = acc;
        }
        #pragma unroll
        for (int o = 0; o < 3; ++o) {
            float acc = 0.f;
            #pragma unroll
            for (int i = 0; i < 6; ++i)
                acc += w2[o * 6 + i] * t[i];
            wsT[tid * 4 + o] = acc;
        }
        wsT[tid * 4 + 3] = 0.f;
        if (tid == 0) {
            float tb[6];
            #pragma unroll
            for (int i = 0; i < 6; ++i) {
                float acc = 0.f;
                #pragma unroll
                for (int j = 0; j < 12; ++j)
                    acc += w1[i * 12 + j] * b0[j];
                tb[i] = acc + b1[i];
            }
            #pragma unroll
            for (int o = 0; o < 3; ++o) {
                float acc = 0.f;
                #pragma unroll
                for (int i = 0; i < 6; ++i)
                    acc += w2[o * 6 + i] * tb[i];
                bc[o] = acc + b2[o];
            }
            bc[3] = 0.f;
        }
    }
    __syncthreads();

    const int lane = tid & 63;
    const int wave = tid >> 6;
    const int bag  = blockIdx.x * (blockDim.x >> 6) + wave;
    if (bag >= num_bags) return;

    const int start = eb_offset[bag];
    const int end   = (bag + 1 < num_bags) ? eb_offset[bag + 1] : n_indices;
    const int cnt   = end - start;

    const float2 x  = *(const float2*)(mlp_input + bag * KDIM + lane * 2);
    const float4 t0 = *(const float4*)(wsT + lane * 8);
    const float4 t1 = *(const float4*)(wsT + lane * 8 + 4);
    float m0 = x.x * t0.x + x.y * t1.x;
    float m1 = x.x * t0.y + x.y * t1.y;
    float m2 = x.x * t0.z + x.y * t1.z;

    float sx = 0.f, sy = 0.f, sz = 0.f;
    if (lane < cnt) {
        const int idx = eb_input[start + lane];
        const F3 r = *(const F3*)(emb_weight + idx * 3);
        sx = r.x; sy = r.y; sz = r.z;
        for (int p = start + lane + 64; p < end; p += 64) {
            const int i2 = eb_input[p];
            const F3 r2 = *(const F3*)(emb_weight + i2 * 3);
            sx += r2.x; sy += r2.y; sz += r2.z;
        }
    }
    #pragma unroll
    for (int off = 1; off <= 32; off <<= 1) {
        sx += __shfl_xor(sx, off, 64);
        sy += __shfl_xor(sy, off, 64);
        sz += __shfl_xor(sz, off, 64);
        m0 += __shfl_xor(m0, off, 64);
        m1 += __shfl_xor(m1, off, 64);
        m2 += __shfl_xor(m2, off, 64);
    }
    if (lane < 12) {
        float v;
        if (lane < 9) {
            const float inv = 1.0f / fmaxf((float)cnt, 1.0f);
            v = (lane % 3 == 0 ? sx : (lane % 3 == 1 ? sy : sz)) * inv;
        } else {
            const int cc = lane - 9;
            v = (cc == 0 ? m0 : (cc == 1 ? m1 : m2)) + bc[cc];
        }
        out[bag * 12 + lane] = v;
    }
}

extern "C" void kernel_launch(void* const* d_in, const int* in_sizes, int n_in,
                              void* d_out, int out_size, void* d_ws, size_t ws_size,
                              hipStream_t stream) {
    const int*   eb_input   = (const int*)d_in[0];   // [N] int32
    const int*   eb_offset  = (const int*)d_in[1];   // [B] int32
    const float* mlp_input  = (const float*)d_in[2]; // [B,128]
    const float* emb_weight = (const float*)d_in[3]; // [10M,3]
    const float* w0 = (const float*)d_in[4];
    const float* b0 = (const float*)d_in[5];
    const float* w1 = (const float*)d_in[6];
    const float* b1 = (const float*)d_in[7];
    const float* w2 = (const float*)d_in[8];
    const float* b2 = (const float*)d_in[9];
    float* out = (float*)d_out;

    const int n_indices = in_sizes[0];
    const int num_bags  = in_sizes[1];

    // ws layout (1 MB-aligned chunks):
    //   [0, 64K)        counts[NB]
    //   [64K, 64K+4)    spill_cnt
    //   [128K, +12B)    tmp[B*3]
    //   [1M, +16M)      pairs[NB*CAP]
    //   [17M, +8N)      spill[N]
    const size_t pairs_off = 1ull << 20;
    const size_t spill_off = pairs_off + (size_t)NB * CAP * 8;
    const size_t needed    = spill_off + (size_t)n_indices * 8;
    char* ws = (char*)d_ws;

    if (ws == nullptr || ws_size < needed || n_indices <= 0) {
        const int grid = (num_bags + 3) / 4;
        fused_embbag_mlp_kernel<<<grid, 256, 0, stream>>>(
            eb_input, eb_offset, mlp_input, emb_weight,
            w0, b0, w1, b1, w2, b2, out, n_indices, num_bags);
        return;
    }

    unsigned int* counts    = (unsigned int*)(ws);
    unsigned int* spill_cnt = (unsigned int*)(ws + 64 * 1024);
    float*        tmp       = (float*)(ws + 128 * 1024);
    unsigned long long* pairs = (unsigned long long*)(ws + pairs_off);
    unsigned long long* spill = (unsigned long long*)(ws + spill_off);

    const int ntmp  = num_bags * 3;
    const int zmax  = (ntmp > NB) ? ntmp : NB;
    zero_kernel<<<(zmax + 255) / 256, 256, 0, stream>>>(counts, spill_cnt, tmp, ntmp);

    scatter_kernel<<<(n_indices + 255) / 256, 256, 0, stream>>>(
        eb_input, eb_offset, counts, spill_cnt, pairs, spill, n_indices, num_bags);

    const long long gtot = (long long)NB * CAP + n_indices;
    gather_kernel<<<(int)((gtot + 255) / 256), 256, 0, stream>>>(
        pairs, spill, counts, spill_cnt, emb_weight, tmp, n_indices);

    finalize_kernel<<<(num_bags + 3) / 4, 256, 0, stream>>>(
        eb_offset, mlp_input, tmp, w0, b0, w1, b1, w2, b2,
        out, n_indices, num_bags);
}

// Round 6
// 195.245 us; speedup vs baseline: 1.8330x; 1.8330x over previous
//
#include <hip/hip_runtime.h>

// B=16384 bags, HIST=50, K=128, EMB_DIM=3. Three chained linears with no
// activation collapse into one 3x128 affine map.
//
// FINAL (v3 revert): single dispatch. Each block redundantly computes the
// collapsed map Wc[3][128] (+bias bc[3]) into LDS (threads 0..127; w0 is
// 6 KB -> L2-resident), then one 64-lane wave per bag: one lane per row,
// full-row dwordx3 gathers, 6-value wave butterfly, 12-lane coalesced store.
//
// Session evidence (rounds 0-5): three structurally independent gather
// implementations (4-round predicated scalar, lane-per-row dwordx3, and a
// count-sorted ascending-address gather pipeline) all converge to
// ~0.9-1.1 TB/s effective on this access pattern — ~819K uniformly-random
// 12 B rows over a 120 MB table with L3 swept each iteration by the 480 MB
// harness re-poison fill (~42 MB of distinct 64 B lines). The ordered-gather
// experiment (v5) measured 911 GB/s and additionally exposed fp32 atomics
// writing through to HBM (76 MB WRITE_SIZE). Request count, dispatch count,
// and access order are all off the critical path; this kernel sits on the
// empirical random-gather ceiling. Remaining dur_us is dominated by two
// ~72 µs harness poison fills (84-86% HBM peak, not controllable).

#define KDIM 128

struct F3 { float x, y, z; };   // 12-byte row; compiles to global_load_dwordx3

__global__ __launch_bounds__(256) void fused_embbag_mlp_kernel(
    const int* __restrict__ eb_input,     // [N] indices (int32)
    const int* __restrict__ eb_offset,    // [B] bag starts
    const float* __restrict__ mlp_input,  // [B, 128]
    const float* __restrict__ emb_weight, // [NUM_EMB, 3]
    const float* __restrict__ w0,         // [12,128]
    const float* __restrict__ b0,         // [12]
    const float* __restrict__ w1,         // [6,12]
    const float* __restrict__ b1,         // [6]
    const float* __restrict__ w2,         // [3,6]
    const float* __restrict__ b2,         // [3]
    float* __restrict__ out,              // [B, 12]
    int n_indices, int num_bags)
{
    // --- Per-block collapse: wsT[k][o] = Wc[o][k], bc[o] ------------------
    __shared__ float wsT[KDIM * 4];   // [128][4] (o=3 is pad)
    __shared__ float bc[4];

    const int tid = threadIdx.x;
    if (tid < KDIM) {
        float t[6];
        #pragma unroll
        for (int i = 0; i < 6; ++i) {
            float acc = 0.f;
            #pragma unroll
            for (int j = 0; j < 12; ++j)
                acc += w1[i * 12 + j] * w0[j * KDIM + tid];
            t[i] = acc;
        }
        #pragma unroll
        for (int o = 0; o < 3; ++o) {
            float acc = 0.f;
            #pragma unroll
            for (int i = 0; i < 6; ++i)
                acc += w2[o * 6 + i] * t[i];
            wsT[tid * 4 + o] = acc;
        }
        wsT[tid * 4 + 3] = 0.f;
        if (tid == 0) {
            float tb[6];
            #pragma unroll
            for (int i = 0; i < 6; ++i) {
                float acc = 0.f;
                #pragma unroll
                for (int j = 0; j < 12; ++j)
                    acc += w1[i * 12 + j] * b0[j];
                tb[i] = acc + b1[i];
            }
            #pragma unroll
            for (int o = 0; o < 3; ++o) {
                float acc = 0.f;
                #pragma unroll
                for (int i = 0; i < 6; ++i)
                    acc += w2[o * 6 + i] * tb[i];
                bc[o] = acc + b2[o];
            }
            bc[3] = 0.f;
        }
    }
    __syncthreads();

    // --- Bag pipeline: one wave per bag -----------------------------------
    const int lane = tid & 63;
    const int wave = tid >> 6;
    const int bag  = blockIdx.x * (blockDim.x >> 6) + wave;
    if (bag >= num_bags) return;

    const int start = eb_offset[bag];
    const int end   = (bag + 1 < num_bags) ? eb_offset[bag + 1] : n_indices;
    const int cnt   = end - start;

    // MLP partials (independent of the gather chain; 32-bit offsets safe)
    const float2 x  = *(const float2*)(mlp_input + bag * KDIM + lane * 2);
    const float4 t0 = *(const float4*)(wsT + lane * 8);
    const float4 t1 = *(const float4*)(wsT + lane * 8 + 4);
    float m0 = x.x * t0.x + x.y * t1.x;
    float m1 = x.x * t0.y + x.y * t1.y;
    float m2 = x.x * t0.z + x.y * t1.z;

    // Embedding gather: lane r owns rows start+r, start+r+64, ...
    float sx = 0.f, sy = 0.f, sz = 0.f;
    if (lane < cnt) {
        const int idx = eb_input[start + lane];
        const F3 r = *(const F3*)(emb_weight + idx * 3);
        sx = r.x; sy = r.y; sz = r.z;
        // Tail (cnt > 64) — never taken for HIST=50
        for (int p = start + lane + 64; p < end; p += 64) {
            const int i2 = eb_input[p];
            const F3 r2 = *(const F3*)(emb_weight + i2 * 3);
            sx += r2.x; sy += r2.y; sz += r2.z;
        }
    }

    // Full-wave butterfly reduction of all 6 partials
    #pragma unroll
    for (int off = 1; off <= 32; off <<= 1) {
        sx += __shfl_xor(sx, off, 64);
        sy += __shfl_xor(sy, off, 64);
        sz += __shfl_xor(sz, off, 64);
        m0 += __shfl_xor(m0, off, 64);
        m1 += __shfl_xor(m1, off, 64);
        m2 += __shfl_xor(m2, off, 64);
    }

    // Epilogue: lanes 0..11 write the 12 columns (coalesced 48 B / bag)
    if (lane < 12) {
        float v;
        if (lane < 9) {
            const float inv = 1.0f / fmaxf((float)cnt, 1.0f);
            const int cc = lane % 3;
            v = (cc == 0 ? sx : (cc == 1 ? sy : sz)) * inv;
        } else {
            const int cc = lane - 9;
            v = (cc == 0 ? m0 : (cc == 1 ? m1 : m2)) + bc[cc];
        }
        out[bag * 12 + lane] = v;
    }
}

extern "C" void kernel_launch(void* const* d_in, const int* in_sizes, int n_in,
                              void* d_out, int out_size, void* d_ws, size_t ws_size,
                              hipStream_t stream) {
    const int*   eb_input   = (const int*)d_in[0];   // [B*HIST] int32
    const int*   eb_offset  = (const int*)d_in[1];   // [B] int32
    const float* mlp_input  = (const float*)d_in[2]; // [B,128]
    const float* emb_weight = (const float*)d_in[3]; // [10M,3]
    const float* w0 = (const float*)d_in[4];
    const float* b0 = (const float*)d_in[5];
    const float* w1 = (const float*)d_in[6];
    const float* b1 = (const float*)d_in[7];
    const float* w2 = (const float*)d_in[8];
    const float* b2 = (const float*)d_in[9];
    float* out = (float*)d_out;
    (void)d_ws; (void)ws_size;

    const int n_indices = in_sizes[0];
    const int num_bags  = in_sizes[1];

    const int waves_per_block = 4;                 // 256 threads
    const int grid = (num_bags + waves_per_block - 1) / waves_per_block;
    fused_embbag_mlp_kernel<<<grid, 256, 0, stream>>>(
        eb_input, eb_offset, mlp_input, emb_weight,
        w0, b0, w1, b1, w2, b2, out, n_indices, num_bags);
}